// Round 20
// baseline (724.700 us; speedup 1.0000x reference)
//
#include <hip/hip_runtime.h>
#include <cstddef>
#include <cstdint>

#define BATCH 32
#define SEQ 2048
#define DM 1024

typedef __attribute__((ext_vector_type(8))) _Float16 half8v;
typedef __attribute__((ext_vector_type(4))) _Float16 half4v;
typedef __attribute__((ext_vector_type(2))) __fp16 fp16x2;   // cvt_pkrtz native type
typedef __attribute__((ext_vector_type(4))) float f32x4;

// Persistent device-global scratch (fully rewritten every launch)
// g_Bpk: Wk_w fp16 in FRAGMENT order [nc 8][sub 8][kt 32][kgrp 4][row 16][e 8] (2 MB).
__device__ _Float16 g_Bpk[8 * 8 * 32 * 4 * 16 * 8];
__device__ float g_q[BATCH * DM];              // q projection (128 KB)
__device__ float g_sp[8][BATCH * SEQ];         // scores partials: slot = nchunk*2 + wn

// tanh(x) = 1 - 2/(e^{2x}+1); saturates to +-1 correctly for |x| large
__device__ __forceinline__ float tanh_fast(float x) {
    float e = __expf(2.0f * x);
    return 1.0f - 2.0f / (e + 1.0f);
}

// ---------------- pack Wk_w -> fp16 fragment-major layout (once, ~4 MB) ----------------
__global__ __launch_bounds__(256) void packb_kernel(const float* __restrict__ Wk_w) {
    int blk = blockIdx.x;              // 0..63 = nc*8 + sub
    int nc = blk >> 3, sub = blk & 7;
    int t = threadIdx.x;
    int row = t & 15, kgrp = (t >> 4) & 3, kt0 = t >> 6;   // kt0: 0..3
    const float* src = Wk_w + (size_t)(nc * 128 + sub * 16 + row) * DM;
    _Float16* dst = g_Bpk + (size_t)blk * 16384;           // block-local [kt][kgrp][row][8]
#pragma unroll
    for (int pass = 0; pass < 8; ++pass) {
        int kt = pass * 4 + kt0;
        float4 w0 = *reinterpret_cast<const float4*>(src + kt * 32 + kgrp * 8);
        float4 w1 = *reinterpret_cast<const float4*>(src + kt * 32 + kgrp * 8 + 4);
        union { _Float16 f[8]; half8v v; } h;
        h.f[0] = (_Float16)w0.x; h.f[1] = (_Float16)w0.y;
        h.f[2] = (_Float16)w0.z; h.f[3] = (_Float16)w0.w;
        h.f[4] = (_Float16)w1.x; h.f[5] = (_Float16)w1.y;
        h.f[6] = (_Float16)w1.z; h.f[7] = (_Float16)w1.w;
        *reinterpret_cast<half8v*>(&dst[(size_t)((kt * 4 + kgrp) * 16 + row) * 8]) = h.v;
    }
}

// ---------------- init: zero context (atomically accumulated) ----------------
__global__ __launch_bounds__(256) void init_kernel(float* __restrict__ context) {
    int idx = blockIdx.x * 256 + threadIdx.x;
    if (idx < BATCH * DM) context[idx] = 0.f;
}

// ---------------- q projection: block per output d; Wq read once total ----------------
__global__ __launch_bounds__(256) void qproj_kernel(const float* __restrict__ query,
                                                    const float* __restrict__ Wq_w,
                                                    const float* __restrict__ Wq_b) {
    int d = blockIdx.x;
    int t = threadIdx.x;
    __shared__ float wrow[DM];
    __shared__ float part[8][32];
    reinterpret_cast<float4*>(wrow)[t] =
        reinterpret_cast<const float4*>(Wq_w + (size_t)d * DM)[t];
    __syncthreads();
    int b = t & 31, seg = t >> 5;
    const float4* qp = reinterpret_cast<const float4*>(query + b * DM + seg * 128);
    const float4* wp = reinterpret_cast<const float4*>(wrow + seg * 128);
    float acc = 0.f;
#pragma unroll
    for (int i = 0; i < 32; ++i) {
        float4 qv = qp[i];
        float4 wv = wp[i];
        acc += qv.x * wv.x + qv.y * wv.y + qv.z * wv.z + qv.w * wv.w;
    }
    part[seg][b] = acc;
    __syncthreads();
    if (t < 32) {
        float s = Wq_b[d];
#pragma unroll
        for (int g = 0; g < 8; ++g) s += part[g][t];
        g_q[t * DM + d] = s;
    }
}

// ---------------- scores: fp16 MFMA GEMM; BN=256, K-tile=128, 1 barrier/128K ------
#define BM 128
#define BN 256
#define NT3 8    // 8 K-tiles of 128 (= 32 sub-tiles of 32)

// Regs: acc 128 + A-stage 32 (time-shared 2x/tile) + B-frags 64 (time-shared) +
// misc ~25 ~= 249 <= 256 @ 2 waves/SIMD. WRITE_SIZE is the spill tripwire.
__global__ __launch_bounds__(256, 2) void scores_kernel(const float* __restrict__ keys,
                                                        const float* __restrict__ Wk_b,
                                                        const float* __restrict__ v_w) {
    // A in LDS: [dbuf][sub 4][kc 4][129 rows][8] fp16; kc-plane pad (129) = 4-bank
    // rotate, conflict-free frag reads. 66 KB -> 2 blocks = 132 KB/CU.
    __shared__ _Float16 AhS[2][4][4][BM + 1][8];

    // XCD-aware order: 2048 blocks = 8 XCDs x 256 slots (bijective); nchunk-minor
    // so the 4 blocks sharing an A-panel are co-resident on one XCD.
    const unsigned bid = blockIdx.x;
    const unsigned L = (bid & 7u) * 256u + (bid >> 3);
    const int mtile = (int)(L >> 2);       // 0..511
    const int nchunk = (int)(L & 3u);      // 0..3
    const int m0 = mtile * BM;
    const int b = m0 >> 11;

    const int t = threadIdx.x;
    const int w = t >> 6, l = t & 63;
    const int wm = w >> 1, wn = w & 1;     // 2x2 waves; wave tile 64m x 128n
    const int lr = l & 15, lg = l >> 4;

    // A staging: 8 contiguous 128B row-segments per inst (proven r9-r19 pattern).
    const int akc = (l & 7) >> 1;          // 0..3
    const int aoff = ((l & 7) & 1) * 4;    // 0 or 4
    const float* Ap = keys + (size_t)(m0 + w * 32 + (l >> 3)) * DM + (l & 7) * 4;

    // Wave's 128-col strip = old-nc unit (nchunk*2 + wn) of the g_Bpk layout.
    // B-frag base: lane l -> contiguous 16B of frag (kgrp=l>>4, row=l&15).
    const int oldnc = nchunk * 2 + wn;
    const _Float16* Bp = g_Bpk + (size_t)oldnc * 8 * 16384
                               + (size_t)(l >> 4) * 128 + (size_t)(l & 15) * 8;

    float4 as0[4], as1[4];   // A staging (time-shared: subs 0,1 then 2,3)
    half8v bE[8], bO[8];     // B-frags (time-shared across the 4 subs)

    f32x4 acc[4][8];
#pragma unroll
    for (int mi = 0; mi < 4; ++mi)
#pragma unroll
        for (int ni = 0; ni < 8; ++ni)
#pragma unroll
            for (int c = 0; c < 4; ++c) acc[mi][ni][c] = 0.f;

    // kt = K-tile index (128-K units); so = starting sub (0 or 2);
    // ks = global 32-K sub index (0..31)
#define LOAD_AS(kt, so)                                                          \
    {                                                                            \
        _Pragma("unroll") for (int j = 0; j < 4; ++j)                            \
            as0[j] = *reinterpret_cast<const float4*>(                           \
                Ap + (size_t)j * 8 * DM + (kt) * 128 + (so) * 32);               \
        _Pragma("unroll") for (int j = 0; j < 4; ++j)                            \
            as1[j] = *reinterpret_cast<const float4*>(                           \
                Ap + (size_t)j * 8 * DM + (kt) * 128 + (so) * 32 + 32);          \
    }
#define LOAD_BF(ks, dst)                                                         \
    {                                                                            \
        _Pragma("unroll") for (int ni = 0; ni < 8; ++ni)                         \
            dst[ni] = *reinterpret_cast<const half8v*>(                          \
                Bp + (size_t)ni * 16384 + (size_t)(ks) * 512);                   \
    }
    // pkrtz staging: 2 VALU per float4
#define STAGE_ONE(bufi, sub, areg)                                               \
    {                                                                            \
        _Pragma("unroll") for (int j = 0; j < 4; ++j) {                          \
            const float* fa = reinterpret_cast<const float*>(&areg[j]);          \
            union { fp16x2 h2[2]; half4v v; } u;                                 \
            u.h2[0] = __builtin_amdgcn_cvt_pkrtz(fa[0], fa[1]);                  \
            u.h2[1] = __builtin_amdgcn_cvt_pkrtz(fa[2], fa[3]);                  \
            *reinterpret_cast<half4v*>(                                          \
                &AhS[bufi][sub][akc][w * 32 + j * 8 + (l >> 3)][aoff]) = u.v;    \
        }                                                                        \
    }
#define COMPUTE_S(bufi, sub, breg)                                               \
    {                                                                            \
        __builtin_amdgcn_s_setprio(1);                                           \
        _Pragma("unroll") for (int mi = 0; mi < 4; ++mi) {                       \
            half8v ahv = *reinterpret_cast<const half8v*>(                       \
                &AhS[bufi][sub][lg][wm * 64 + mi * 16 + lr][0]);                 \
            _Pragma("unroll") for (int ni = 0; ni < 8; ++ni)                     \
                acc[mi][ni] = __builtin_amdgcn_mfma_f32_16x16x32_f16(            \
                    ahv, breg[ni], acc[mi][ni], 0, 0, 0);                        \
        }                                                                        \
        __builtin_amdgcn_s_setprio(0);                                          \
    }
    // LDS hazards only need lgkmcnt; global loads ride the barrier (compiler
    // scoreboard inserts counted vmcnt before each register use).
#define SYNC()                                                                   \
    asm volatile("s_waitcnt lgkmcnt(0)" ::: "memory");                           \
    __builtin_amdgcn_s_barrier();                                                \
    asm volatile("" ::: "memory");

    // ---- prologue: K-tile 0 (all 4 subs) -> buf0; B(ks=0) -> bE ----
    LOAD_AS(0, 0);
    LOAD_BF(0, bE);
    STAGE_ONE(0, 0, as0);       // scoreboard waits as regs
    STAGE_ONE(0, 1, as1);
    LOAD_AS(0, 2);
    STAGE_ONE(0, 2, as0);
    STAGE_ONE(0, 3, as1);
    SYNC()

    // ---- main loop: one barrier per 128-K tile; 128 MFMA/wave per interval ----
    // B regs alternate bE/bO across subs; A regs refilled twice per tile.
    // Buffer read this tile (cb) is re-staged only NEXT tile, after the
    // lgkm-drain + barrier -> race-free (r18/r19 discipline).
    for (int tt = 0; tt < NT3; ++tt) {
        const int cb = tt & 1;
        LOAD_BF(4 * tt + 1, bO);
        if (tt + 1 < NT3) LOAD_AS(tt + 1, 0);
        COMPUTE_S(cb, 0, bE);
        LOAD_BF(4 * tt + 2, bE);
        COMPUTE_S(cb, 1, bO);
        if (tt + 1 < NT3) {
            STAGE_ONE(cb ^ 1, 0, as0);
            STAGE_ONE(cb ^ 1, 1, as1);
        }
        LOAD_BF(4 * tt + 3, bO);
        if (tt + 1 < NT3) LOAD_AS(tt + 1, 2);
        COMPUTE_S(cb, 2, bE);
        if (tt + 1 < NT3) LOAD_BF(4 * tt + 4, bE);
        COMPUTE_S(cb, 3, bO);
        if (tt + 1 < NT3) {
            STAGE_ONE(cb ^ 1, 2, as0);
            STAGE_ONE(cb ^ 1, 3, as1);
        }
        SYNC()
    }

    // epilogue: tanh * v_w, reduce over this wave's 128 n-cols.
    // Slot = nchunk*2 + wn = oldnc: exactly ONE writer per (slot,row).
    float qb[8], vw[8];
#pragma unroll
    for (int ni = 0; ni < 8; ++ni) {
        int n = oldnc * 128 + ni * 16 + lr;
        qb[ni] = g_q[b * DM + n] + Wk_b[n];
        vw[ni] = v_w[n];
    }
#pragma unroll
    for (int mi = 0; mi < 4; ++mi) {
#pragma unroll
        for (int rg = 0; rg < 4; ++rg) {
            float p = 0.f;
#pragma unroll
            for (int ni = 0; ni < 8; ++ni) {
                float val = acc[mi][ni][rg] + qb[ni];
                p += tanh_fast(val) * vw[ni];
            }
#pragma unroll
            for (int off = 8; off >= 1; off >>= 1) p += __shfl_xor(p, off, 16);
            if (lr == 0)
                g_sp[oldnc][m0 + wm * 64 + mi * 16 + lg * 4 + rg] = p;
        }
    }
#undef LOAD_AS
#undef LOAD_BF
#undef STAGE_ONE
#undef COMPUTE_S
#undef SYNC
}

// ---------------- softmax over S per batch row (sums the 8 partial slots) --------
__global__ __launch_bounds__(256) void softmax_kernel(float* __restrict__ attn) {
    int b = blockIdx.x;
    int tid = threadIdx.x;
    __shared__ float redm[4];
    __shared__ float reds[4];
    float v[8];
    float mx = -1e30f;
#pragma unroll
    for (int i = 0; i < 8; ++i) {
        int idx = b * SEQ + i * 256 + tid;
        float s = 0.f;
#pragma unroll
        for (int pslot = 0; pslot < 8; ++pslot) s += g_sp[pslot][idx];
        v[i] = s;
        mx = fmaxf(mx, v[i]);
    }
#pragma unroll
    for (int off = 32; off >= 1; off >>= 1) mx = fmaxf(mx, __shfl_xor(mx, off));
    int wid = tid >> 6;
    if ((tid & 63) == 0) redm[wid] = mx;
    __syncthreads();
    mx = fmaxf(fmaxf(redm[0], redm[1]), fmaxf(redm[2], redm[3]));
    float sum = 0.f;
#pragma unroll
    for (int i = 0; i < 8; ++i) {
        v[i] = expf(v[i] - mx);
        sum += v[i];
    }
#pragma unroll
    for (int off = 32; off >= 1; off >>= 1) sum += __shfl_xor(sum, off);
    if ((tid & 63) == 0) reds[wid] = sum;
    __syncthreads();
    sum = reds[0] + reds[1] + reds[2] + reds[3];
    float inv = 1.f / sum;
#pragma unroll
    for (int i = 0; i < 8; ++i) attn[b * SEQ + i * 256 + tid] = v[i] * inv;
}

// ---------------- context = attn @ keys (coalesced float4 rows; keys is L3-hot) ------
__global__ __launch_bounds__(256) void context_kernel(const float* __restrict__ keys,
                                                      const float* __restrict__ attn,
                                                      float* __restrict__ context) {
    int id = blockIdx.x;              // 32 b x 16 schunk = 512 blocks
    int schunk = id & 15;
    int b = id >> 4;
    int tid = threadIdx.x;
    __shared__ float a_s[128];
    if (tid < 128) a_s[tid] = attn[b * SEQ + schunk * 128 + tid];
    __syncthreads();
    const float4* kp =
        reinterpret_cast<const float4*>(keys + ((size_t)b * SEQ + schunk * 128) * DM) + tid;
    float4 acc = {0.f, 0.f, 0.f, 0.f};
#pragma unroll 4
    for (int s = 0; s < 128; ++s) {
        float4 kv = kp[(size_t)s * (DM / 4)];
        float a = a_s[s];
        acc.x += a * kv.x; acc.y += a * kv.y; acc.z += a * kv.z; acc.w += a * kv.w;
    }
    atomicAdd(&context[b * DM + tid * 4 + 0], acc.x);
    atomicAdd(&context[b * DM + tid * 4 + 1], acc.y);
    atomicAdd(&context[b * DM + tid * 4 + 2], acc.z);
    atomicAdd(&context[b * DM + tid * 4 + 3], acc.w);
}

extern "C" void kernel_launch(void* const* d_in, const int* in_sizes, int n_in,
                              void* d_out, int out_size, void* d_ws, size_t ws_size,
                              hipStream_t stream) {
    const float* query = (const float*)d_in[0];
    const float* keys  = (const float*)d_in[1];
    const float* Wq_w  = (const float*)d_in[2];
    const float* Wq_b  = (const float*)d_in[3];
    const float* Wk_w  = (const float*)d_in[4];
    const float* Wk_b  = (const float*)d_in[5];
    const float* v_w   = (const float*)d_in[6];
    // d_in[7] = v_b: additive constant on all scores -> cancels exactly in softmax.

    float* context = (float*)d_out;              // [32][1024]
    float* attn    = context + BATCH * DM;       // [32][2048]

    hipLaunchKernelGGL(packb_kernel, dim3(64), dim3(256), 0, stream, Wk_w);
    hipLaunchKernelGGL(init_kernel, dim3(128), dim3(256), 0, stream, context);
    hipLaunchKernelGGL(qproj_kernel, dim3(DM), dim3(256), 0, stream, query, Wq_w, Wq_b);
    hipLaunchKernelGGL(scores_kernel, dim3((BATCH * SEQ / BM) * (DM / BN)), dim3(256), 0, stream,
                       keys, Wk_b, v_w);
    hipLaunchKernelGGL(softmax_kernel, dim3(BATCH), dim3(256), 0, stream, attn);
    hipLaunchKernelGGL(context_kernel, dim3(512), dim3(256), 0, stream, keys, attn, context);
}

// Round 21
// 236.294 us; speedup vs baseline: 3.0669x; 3.0669x over previous
//
#include <hip/hip_runtime.h>
#include <cstddef>
#include <cstdint>

#define BATCH 32
#define SEQ 2048
#define DM 1024

typedef __attribute__((ext_vector_type(8))) _Float16 half8v;
typedef __attribute__((ext_vector_type(4))) _Float16 half4v;
typedef __attribute__((ext_vector_type(2))) __fp16 fp16x2;   // cvt_pkrtz native type
typedef __attribute__((ext_vector_type(4))) float f32x4;

// Persistent device-global scratch (fully rewritten every launch)
// g_Bpk: Wk_w fp16 in FRAGMENT order [nc 8][sub 8][kt 32][kgrp 4][row 16][e 8] (2 MB).
__device__ _Float16 g_Bpk[8 * 8 * 32 * 4 * 16 * 8];
__device__ float g_q[BATCH * DM];              // q projection (128 KB)
__device__ float g_sp[8][BATCH * SEQ];         // scores partials: slot = nchunk*2 + wn

// tanh(x) = 1 - 2/(e^{2x}+1); saturates to +-1 correctly for |x| large
__device__ __forceinline__ float tanh_fast(float x) {
    float e = __expf(2.0f * x);
    return 1.0f - 2.0f / (e + 1.0f);
}

// ---------------- pack Wk_w -> fp16 fragment-major layout (once, ~4 MB) ----------------
__global__ __launch_bounds__(256) void packb_kernel(const float* __restrict__ Wk_w) {
    int blk = blockIdx.x;              // 0..63 = nc*8 + sub
    int nc = blk >> 3, sub = blk & 7;
    int t = threadIdx.x;
    int row = t & 15, kgrp = (t >> 4) & 3, kt0 = t >> 6;   // kt0: 0..3
    const float* src = Wk_w + (size_t)(nc * 128 + sub * 16 + row) * DM;
    _Float16* dst = g_Bpk + (size_t)blk * 16384;           // block-local [kt][kgrp][row][8]
#pragma unroll
    for (int pass = 0; pass < 8; ++pass) {
        int kt = pass * 4 + kt0;
        float4 w0 = *reinterpret_cast<const float4*>(src + kt * 32 + kgrp * 8);
        float4 w1 = *reinterpret_cast<const float4*>(src + kt * 32 + kgrp * 8 + 4);
        union { _Float16 f[8]; half8v v; } h;
        h.f[0] = (_Float16)w0.x; h.f[1] = (_Float16)w0.y;
        h.f[2] = (_Float16)w0.z; h.f[3] = (_Float16)w0.w;
        h.f[4] = (_Float16)w1.x; h.f[5] = (_Float16)w1.y;
        h.f[6] = (_Float16)w1.z; h.f[7] = (_Float16)w1.w;
        *reinterpret_cast<half8v*>(&dst[(size_t)((kt * 4 + kgrp) * 16 + row) * 8]) = h.v;
    }
}

// ---------------- init: zero context (atomically accumulated) ----------------
__global__ __launch_bounds__(256) void init_kernel(float* __restrict__ context) {
    int idx = blockIdx.x * 256 + threadIdx.x;
    if (idx < BATCH * DM) context[idx] = 0.f;
}

// ---------------- q projection: block per output d; Wq read once total ----------------
__global__ __launch_bounds__(256) void qproj_kernel(const float* __restrict__ query,
                                                    const float* __restrict__ Wq_w,
                                                    const float* __restrict__ Wq_b) {
    int d = blockIdx.x;
    int t = threadIdx.x;
    __shared__ float wrow[DM];
    __shared__ float part[8][32];
    reinterpret_cast<float4*>(wrow)[t] =
        reinterpret_cast<const float4*>(Wq_w + (size_t)d * DM)[t];
    __syncthreads();
    int b = t & 31, seg = t >> 5;
    const float4* qp = reinterpret_cast<const float4*>(query + b * DM + seg * 128);
    const float4* wp = reinterpret_cast<const float4*>(wrow + seg * 128);
    float acc = 0.f;
#pragma unroll
    for (int i = 0; i < 32; ++i) {
        float4 qv = qp[i];
        float4 wv = wp[i];
        acc += qv.x * wv.x + qv.y * wv.y + qv.z * wv.z + qv.w * wv.w;
    }
    part[seg][b] = acc;
    __syncthreads();
    if (t < 32) {
        float s = Wq_b[d];
#pragma unroll
        for (int g = 0; g < 8; ++g) s += part[g][t];
        g_q[t * DM + d] = s;
    }
}

// ---------------- scores: fp16 MFMA GEMM; BN=256, K-tile=64, 1 barrier/64K ------
#define BM 128
#define BN 256
#define NT2 16   // 16 K-tiles of 64 (= 32 sub-tiles of 32)

// Regs: acc 128 + A-stage 32 + B-frags 64 + misc ~25 ~= 249 <= 256 @ 2 waves/SIMD.
// K-tile=128 variant (r20) needs ~280 -> spills 1.4 GB scratch. This is the
// register-feasible optimum of the family.
__global__ __launch_bounds__(256, 2) void scores_kernel(const float* __restrict__ keys,
                                                        const float* __restrict__ Wk_b,
                                                        const float* __restrict__ v_w) {
    // A in LDS: [dbuf][sub][kc 4][129 rows][8] fp16; kc-plane pad (129) = 4-bank
    // rotate, conflict-free frag reads. 33 KB.
    __shared__ _Float16 AhS[2][2][4][BM + 1][8];

    // XCD-aware order: 2048 blocks = 8 XCDs x 256 slots (bijective); nchunk-minor
    // so the 4 blocks sharing an A-panel are co-resident on one XCD.
    const unsigned bid = blockIdx.x;
    const unsigned L = (bid & 7u) * 256u + (bid >> 3);
    const int mtile = (int)(L >> 2);       // 0..511
    const int nchunk = (int)(L & 3u);      // 0..3
    const int m0 = mtile * BM;
    const int b = m0 >> 11;

    const int t = threadIdx.x;
    const int w = t >> 6, l = t & 63;
    const int wm = w >> 1, wn = w & 1;     // 2x2 waves; wave tile 64m x 128n
    const int lr = l & 15, lg = l >> 4;

    // A staging: 8 contiguous 128B row-segments per inst (proven r9-r19 pattern).
    const int akc = (l & 7) >> 1;          // 0..3
    const int aoff = ((l & 7) & 1) * 4;    // 0 or 4
    const float* Ap = keys + (size_t)(m0 + w * 32 + (l >> 3)) * DM + (l & 7) * 4;

    // Wave's 128-col strip = old-nc unit (nchunk*2 + wn) of the g_Bpk layout.
    // B-frag base: lane l -> contiguous 16B of frag (kgrp=l>>4, row=l&15).
    const int oldnc = nchunk * 2 + wn;
    const _Float16* Bp = g_Bpk + (size_t)oldnc * 8 * 16384
                               + (size_t)(l >> 4) * 128 + (size_t)(l & 15) * 8;

    float4 as0[4], as1[4];   // A staging: the two 32-K subs of the NEXT K-tile
    half8v bE[8], bO[8];     // B-frags: bE = sub0, bO = sub1 (named: rule #20)

    f32x4 acc[4][8];
#pragma unroll
    for (int mi = 0; mi < 4; ++mi)
#pragma unroll
        for (int ni = 0; ni < 8; ++ni)
#pragma unroll
            for (int c = 0; c < 4; ++c) acc[mi][ni][c] = 0.f;

    // kt = K-tile index (64-K units); ks = sub-tile index (32-K units)
#define LOAD_A2(kt)                                                              \
    {                                                                            \
        _Pragma("unroll") for (int j = 0; j < 4; ++j)                            \
            as0[j] = *reinterpret_cast<const float4*>(                           \
                Ap + (size_t)j * 8 * DM + (kt) * 64);                            \
        _Pragma("unroll") for (int j = 0; j < 4; ++j)                            \
            as1[j] = *reinterpret_cast<const float4*>(                           \
                Ap + (size_t)j * 8 * DM + (kt) * 64 + 32);                       \
    }
#define LOAD_BF(ks, dst)                                                         \
    {                                                                            \
        _Pragma("unroll") for (int ni = 0; ni < 8; ++ni)                         \
            dst[ni] = *reinterpret_cast<const half8v*>(                          \
                Bp + (size_t)ni * 16384 + (size_t)(ks) * 512);                   \
    }
    // pkrtz staging: 2 VALU per float4
#define STAGE_ONE(bufi, sub, areg)                                               \
    {                                                                            \
        _Pragma("unroll") for (int j = 0; j < 4; ++j) {                          \
            const float* fa = reinterpret_cast<const float*>(&areg[j]);          \
            union { fp16x2 h2[2]; half4v v; } u;                                 \
            u.h2[0] = __builtin_amdgcn_cvt_pkrtz(fa[0], fa[1]);                  \
            u.h2[1] = __builtin_amdgcn_cvt_pkrtz(fa[2], fa[3]);                  \
            *reinterpret_cast<half4v*>(                                          \
                &AhS[bufi][sub][akc][w * 32 + j * 8 + (l >> 3)][aoff]) = u.v;    \
        }                                                                        \
    }
#define COMPUTE_S(bufi, sub, breg)                                               \
    {                                                                            \
        __builtin_amdgcn_s_setprio(1);                                           \
        _Pragma("unroll") for (int mi = 0; mi < 4; ++mi) {                       \
            half8v ahv = *reinterpret_cast<const half8v*>(                       \
                &AhS[bufi][sub][lg][wm * 64 + mi * 16 + lr][0]);                 \
            _Pragma("unroll") for (int ni = 0; ni < 8; ++ni)                     \
                acc[mi][ni] = __builtin_amdgcn_mfma_f32_16x16x32_f16(            \
                    ahv, breg[ni], acc[mi][ni], 0, 0, 0);                        \
        }                                                                        \
        __builtin_amdgcn_s_setprio(0);                                          \
    }
    // LDS hazards only need lgkmcnt; global loads ride the barrier (compiler
    // scoreboard inserts counted vmcnt before each register use).
#define SYNC()                                                                   \
    asm volatile("s_waitcnt lgkmcnt(0)" ::: "memory");                           \
    __builtin_amdgcn_s_barrier();                                                \
    asm volatile("" ::: "memory");

    // ---- prologue: K-tile 0 -> buf0; B(sub0=0) -> bE ----
    LOAD_A2(0);
    LOAD_BF(0, bE);
    STAGE_ONE(0, 0, as0);       // scoreboard waits as regs
    STAGE_ONE(0, 1, as1);
    SYNC()

    // ---- main loop: one barrier per 64-K tile; 64 MFMA/wave per interval ----
    for (int tt = 0; tt < NT2; ++tt) {
        const int cb = tt & 1;
        LOAD_BF(2 * tt + 1, bO);
        if (tt + 1 < NT2) LOAD_A2(tt + 1);
        COMPUTE_S(cb, 0, bE);
        COMPUTE_S(cb, 1, bO);
        if (tt + 1 < NT2) {
            STAGE_ONE(cb ^ 1, 0, as0);
            STAGE_ONE(cb ^ 1, 1, as1);
            LOAD_BF(2 * tt + 2, bE);
        }
        SYNC()
    }

    // epilogue: tanh * v_w, reduce over this wave's 128 n-cols.
    // Slot = nchunk*2 + wn = oldnc: exactly ONE writer per (slot,row).
    float qb[8], vw[8];
#pragma unroll
    for (int ni = 0; ni < 8; ++ni) {
        int n = oldnc * 128 + ni * 16 + lr;
        qb[ni] = g_q[b * DM + n] + Wk_b[n];
        vw[ni] = v_w[n];
    }
#pragma unroll
    for (int mi = 0; mi < 4; ++mi) {
#pragma unroll
        for (int rg = 0; rg < 4; ++rg) {
            float p = 0.f;
#pragma unroll
            for (int ni = 0; ni < 8; ++ni) {
                float val = acc[mi][ni][rg] + qb[ni];
                p += tanh_fast(val) * vw[ni];
            }
#pragma unroll
            for (int off = 8; off >= 1; off >>= 1) p += __shfl_xor(p, off, 16);
            if (lr == 0)
                g_sp[oldnc][m0 + wm * 64 + mi * 16 + lg * 4 + rg] = p;
        }
    }
#undef LOAD_A2
#undef LOAD_BF
#undef STAGE_ONE
#undef COMPUTE_S
#undef SYNC
}

// ---------------- softmax over S per batch row (sums the 8 partial slots) --------
__global__ __launch_bounds__(256) void softmax_kernel(float* __restrict__ attn) {
    int b = blockIdx.x;
    int tid = threadIdx.x;
    __shared__ float redm[4];
    __shared__ float reds[4];
    float v[8];
    float mx = -1e30f;
#pragma unroll
    for (int i = 0; i < 8; ++i) {
        int idx = b * SEQ + i * 256 + tid;
        float s = 0.f;
#pragma unroll
        for (int pslot = 0; pslot < 8; ++pslot) s += g_sp[pslot][idx];
        v[i] = s;
        mx = fmaxf(mx, v[i]);
    }
#pragma unroll
    for (int off = 32; off >= 1; off >>= 1) mx = fmaxf(mx, __shfl_xor(mx, off));
    int wid = tid >> 6;
    if ((tid & 63) == 0) redm[wid] = mx;
    __syncthreads();
    mx = fmaxf(fmaxf(redm[0], redm[1]), fmaxf(redm[2], redm[3]));
    float sum = 0.f;
#pragma unroll
    for (int i = 0; i < 8; ++i) {
        v[i] = expf(v[i] - mx);
        sum += v[i];
    }
#pragma unroll
    for (int off = 32; off >= 1; off >>= 1) sum += __shfl_xor(sum, off);
    if ((tid & 63) == 0) reds[wid] = sum;
    __syncthreads();
    sum = reds[0] + reds[1] + reds[2] + reds[3];
    float inv = 1.f / sum;
#pragma unroll
    for (int i = 0; i < 8; ++i) attn[b * SEQ + i * 256 + tid] = v[i] * inv;
}

// ---------------- context = attn @ keys (coalesced float4 rows; keys is L3-hot) ------
__global__ __launch_bounds__(256) void context_kernel(const float* __restrict__ keys,
                                                      const float* __restrict__ attn,
                                                      float* __restrict__ context) {
    int id = blockIdx.x;              // 32 b x 16 schunk = 512 blocks
    int schunk = id & 15;
    int b = id >> 4;
    int tid = threadIdx.x;
    __shared__ float a_s[128];
    if (tid < 128) a_s[tid] = attn[b * SEQ + schunk * 128 + tid];
    __syncthreads();
    const float4* kp =
        reinterpret_cast<const float4*>(keys + ((size_t)b * SEQ + schunk * 128) * DM) + tid;
    float4 acc = {0.f, 0.f, 0.f, 0.f};
#pragma unroll 4
    for (int s = 0; s < 128; ++s) {
        float4 kv = kp[(size_t)s * (DM / 4)];
        float a = a_s[s];
        acc.x += a * kv.x; acc.y += a * kv.y; acc.z += a * kv.z; acc.w += a * kv.w;
    }
    atomicAdd(&context[b * DM + tid * 4 + 0], acc.x);
    atomicAdd(&context[b * DM + tid * 4 + 1], acc.y);
    atomicAdd(&context[b * DM + tid * 4 + 2], acc.z);
    atomicAdd(&context[b * DM + tid * 4 + 3], acc.w);
}

extern "C" void kernel_launch(void* const* d_in, const int* in_sizes, int n_in,
                              void* d_out, int out_size, void* d_ws, size_t ws_size,
                              hipStream_t stream) {
    const float* query = (const float*)d_in[0];
    const float* keys  = (const float*)d_in[1];
    const float* Wq_w  = (const float*)d_in[2];
    const float* Wq_b  = (const float*)d_in[3];
    const float* Wk_w  = (const float*)d_in[4];
    const float* Wk_b  = (const float*)d_in[5];
    const float* v_w   = (const float*)d_in[6];
    // d_in[7] = v_b: additive constant on all scores -> cancels exactly in softmax.

    float* context = (float*)d_out;              // [32][1024]
    float* attn    = context + BATCH * DM;       // [32][2048]

    hipLaunchKernelGGL(packb_kernel, dim3(64), dim3(256), 0, stream, Wk_w);
    hipLaunchKernelGGL(init_kernel, dim3(128), dim3(256), 0, stream, context);
    hipLaunchKernelGGL(qproj_kernel, dim3(DM), dim3(256), 0, stream, query, Wq_w, Wq_b);
    hipLaunchKernelGGL(scores_kernel, dim3((BATCH * SEQ / BM) * (DM / BN)), dim3(256), 0, stream,
                       keys, Wk_b, v_w);
    hipLaunchKernelGGL(softmax_kernel, dim3(BATCH), dim3(256), 0, stream, attn);
    hipLaunchKernelGGL(context_kernel, dim3(512), dim3(256), 0, stream, keys, attn, context);
}